// Round 1
// baseline (130.209 us; speedup 1.0000x reference)
//
#include <hip/hip_runtime.h>
#include <math.h>

// GMM score, rescaled: out_j = (E_w[td] - x_j) / sigma2_j
// with w_i = exp(-0.5 (td_i - x_j)^2 / sigma2_j), sigma2_j = (exp(2 t_j ln25)-1)/(2 ln25)
//
// B = N = 16384. Compute-bound: 268M exp evaluations on the transcendental pipe.
// Split N into slices so the grid saturates 256 CUs; combine partials with atomics.

#define BLK 256   // threads per block = j's per block
#define CH  512   // train-data chunk per N-slice (LDS staging, 2 KB)

__global__ void zero_kernel(float* __restrict__ p, int n) {
  int i = blockIdx.x * blockDim.x + threadIdx.x;
  if (i < n) p[i] = 0.0f;
}

__launch_bounds__(BLK)
__global__ void gmm_partial(const float* __restrict__ x,
                            const float* __restrict__ t,
                            const float* __restrict__ td,
                            float* __restrict__ wsNum,
                            float* __restrict__ wsDen,
                            int N) {
  __shared__ float lds[CH];
  const int tid = threadIdx.x;
  const int j   = blockIdx.x * BLK + tid;   // output index
  const int s   = blockIdx.y;               // N-slice index
  const int base = s * CH;

  // stage this block's train slice into LDS (coalesced)
  for (int i = tid; i < CH; i += BLK) {
    int gi = base + i;
    lds[i] = (gi < N) ? td[gi] : 0.0f;  // N % CH == 0 in practice; guard is free
  }

  const float xj = x[j];
  const float tj = t[j];
  const float TWO_LOG_S = 6.4377516497364011f;   // 2*ln(25)
  const float LOG2E     = 1.4426950408889634f;
  // sigma2 per reference: (exp(2 t ln25) - 1) / (2 ln25)
  const float sigma2 = (__expf(TWO_LOG_S * tj) - 1.0f) / TWO_LOG_S;
  // fold -0.5/sigma2 and the natural->base2 conversion into one constant
  const float c2 = -0.5f * LOG2E / sigma2;
  __syncthreads();

  // 4 independent accumulator chains for ILP (exp latency hiding)
  float num0 = 0.f, num1 = 0.f, num2 = 0.f, num3 = 0.f;
  float den0 = 0.f, den1 = 0.f, den2 = 0.f, den3 = 0.f;

  const float4* l4 = (const float4*)lds;   // ds_read_b128 broadcast (conflict-free)
  const int iters = CH / 4;
  #pragma unroll 4
  for (int i = 0; i < iters; ++i) {
    float4 v = l4[i];
    // keep the stabilized (td-x)^2 form: arg <= 0 always, no overflow,
    // per-weight relative error ~1e-7 (vs ~1e-3 for the expanded form at small sigma)
    float d0 = v.x - xj, d1 = v.y - xj, d2 = v.z - xj, d3 = v.w - xj;
    float p0 = exp2f(d0 * c2 * d0);   // v_exp_f32, native 2^x
    float p1 = exp2f(d1 * c2 * d1);
    float p2 = exp2f(d2 * c2 * d2);
    float p3 = exp2f(d3 * c2 * d3);
    den0 += p0; den1 += p1; den2 += p2; den3 += p3;
    num0 = fmaf(p0, v.x, num0);
    num1 = fmaf(p1, v.y, num1);
    num2 = fmaf(p2, v.z, num2);
    num3 = fmaf(p3, v.w, num3);
  }
  float num = (num0 + num1) + (num2 + num3);
  float den = (den0 + den1) + (den2 + den3);

  // combine the 32 N-slices; unique address per j within a block, low contention
  atomicAdd(&wsNum[j], num);
  atomicAdd(&wsDen[j], den);
}

__global__ void gmm_final(const float* __restrict__ x,
                          const float* __restrict__ t,
                          const float* __restrict__ wsNum,
                          const float* __restrict__ wsDen,
                          float* __restrict__ out, int B) {
  int j = blockIdx.x * blockDim.x + threadIdx.x;
  if (j >= B) return;
  const float TWO_LOG_S = 6.4377516497364011f;
  float sigma2 = (__expf(TWO_LOG_S * t[j]) - 1.0f) / TWO_LOG_S;
  float den = wsDen[j];
  float num = wsNum[j];
  float evals = (den == 0.0f) ? 0.0f : (num / den);   // reference's den==0 guard
  out[j] = (evals - x[j]) / sigma2;
}

extern "C" void kernel_launch(void* const* d_in, const int* in_sizes, int n_in,
                              void* d_out, int out_size, void* d_ws, size_t ws_size,
                              hipStream_t stream) {
  const float* x  = (const float*)d_in[0];   // (B,1) flat
  const float* t  = (const float*)d_in[1];   // (B,)
  const float* td = (const float*)d_in[2];   // (N,1) flat
  float* out = (float*)d_out;

  const int B = in_sizes[0];
  const int N = in_sizes[2];

  float* wsNum = (float*)d_ws;     // B floats
  float* wsDen = wsNum + B;        // B floats  (total 128 KB of d_ws)

  const int nzero = 2 * B;
  zero_kernel<<<(nzero + 255) / 256, 256, 0, stream>>>(wsNum, nzero);

  const int S = (N + CH - 1) / CH;           // 32 slices
  dim3 grid(B / BLK, S);                     // (64, 32) = 2048 blocks
  gmm_partial<<<grid, BLK, 0, stream>>>(x, t, td, wsNum, wsDen, N);

  gmm_final<<<(B + BLK - 1) / BLK, BLK, 0, stream>>>(x, t, wsNum, wsDen, out, B);
}

// Round 2
// 100.133 us; speedup vs baseline: 1.3004x; 1.3004x over previous
//
#include <hip/hip_runtime.h>
#include <math.h>

// GMM score, rescaled: out_j = (E_w[td] - x_j) / sigma2_j
// w_i = exp(-0.5 (td_i - x_j)^2 / sigma2_j), sigma2_j = (exp(2 t_j ln25)-1)/(2 ln25)
//
// B = N = 16384, d = 1. 268M exp evals -> VALU-issue-bound (R1: VALUBusy 95%).
// R2 changes:
//  - packed f32 math (v_pk_add/mul/fma_f32) via float2 ext-vectors: halves the
//    issue cycles of all non-transcendental ops (wave64 VALU = 2 cyc/instr,
//    pk does 2 elements per instr)
//  - raw v_exp_f32 via __builtin_amdgcn_exp2f: skips the OCML denormal fixup
//    (~4-5 extra VALU/exp). Args are <= 0; HW flush-to-zero below 2^-126 is
//    exactly the desired weight underflow.
//  - per-slice partials into disjoint workspace (2 MB) instead of
//    zero-kernel + atomics: 3 dispatches -> 2. Atomic path kept as runtime
//    fallback if ws_size is too small.

typedef float v2f __attribute__((ext_vector_type(2)));

#define BLK   256
#define MAXCH 1024   // LDS floats per slice (4 KB)

#if __has_builtin(__builtin_amdgcn_exp2f)
#define EXP2(x) __builtin_amdgcn_exp2f(x)
#else
#define EXP2(x) exp2f(x)
#endif

__device__ __forceinline__ float sigma2_of(float tj) {
  const float TWO_LOG_S = 6.4377516497364011f;   // 2*ln(25)
  return (__expf(TWO_LOG_S * tj) - 1.0f) / TWO_LOG_S;
}

template <bool ATOMIC>
__launch_bounds__(BLK)
__global__ void gmm_partial(const float* __restrict__ x,
                            const float* __restrict__ t,
                            const float* __restrict__ td,
                            float* __restrict__ ws,
                            int N, int B, int CH) {
  __shared__ float lds[MAXCH];
  const int tid  = threadIdx.x;
  const int j    = blockIdx.x * BLK + tid;   // output index
  const int s    = blockIdx.y;               // N-slice
  const int S    = gridDim.y;
  const int base = s * CH;

  for (int i = tid; i < CH; i += BLK) {
    int gi = base + i;
    // pad with huge value -> d^2 = inf -> arg = -inf -> exp2 = 0 (weightless)
    lds[i] = (gi < N) ? td[gi] : 1e30f;
  }

  float xj = 0.0f, c2 = -1.0f;
  if (j < B) {
    xj = x[j];
    const float LOG2E = 1.4426950408889634f;
    c2 = -0.5f * LOG2E / sigma2_of(t[j]);   // arg = c2 * (td - x)^2, base-2
  }
  __syncthreads();

  const v2f xv = {xj, xj};
  const v2f cv = {c2, c2};
  v2f num0 = {0.f, 0.f}, num1 = {0.f, 0.f};
  v2f den0 = {0.f, 0.f}, den1 = {0.f, 0.f};

  const float4* l4 = (const float4*)lds;   // ds_read_b128 broadcast, conflict-free
  const int iters = CH >> 2;
  #pragma unroll 4
  for (int i = 0; i < iters; ++i) {
    float4 v = l4[i];
    v2f va = {v.x, v.y}, vb = {v.z, v.w};
    v2f da = va - xv;           // v_pk_add_f32 (neg mod)
    v2f db = vb - xv;
    v2f qa = da * da;           // v_pk_mul_f32  (stabilized form: no cancellation)
    v2f qb = db * db;
    v2f aa = qa * cv;           // v_pk_mul_f32
    v2f ab = qb * cv;
    v2f pa, pb;
    pa.x = EXP2(aa.x);          // raw v_exp_f32
    pa.y = EXP2(aa.y);
    pb.x = EXP2(ab.x);
    pb.y = EXP2(ab.y);
    den0 += pa;                 // v_pk_add_f32
    den1 += pb;
    num0 = __builtin_elementwise_fma(pa, va, num0);   // v_pk_fma_f32
    num1 = __builtin_elementwise_fma(pb, vb, num1);
  }
  float num = (num0.x + num0.y) + (num1.x + num1.y);
  float den = (den0.x + den0.y) + (den1.x + den1.y);

  if (j < B) {
    if (ATOMIC) {
      atomicAdd(&ws[j], num);
      atomicAdd(&ws[B + j], den);
    } else {
      ws[(size_t)s * B + j]       = num;   // num partials: [S][B]
      ws[(size_t)(S + s) * B + j] = den;   // den partials: [S][B]
    }
  }
}

// Reduces S (num,den) partials per j, then the epilogue. Atomic path uses S=1.
__global__ void gmm_final(const float* __restrict__ x,
                          const float* __restrict__ t,
                          const float* __restrict__ ws,
                          float* __restrict__ out, int B, int S) {
  int j = blockIdx.x * blockDim.x + threadIdx.x;
  if (j >= B) return;
  float num = 0.f, den = 0.f;
  for (int s = 0; s < S; ++s) {
    num += ws[(size_t)s * B + j];
    den += ws[(size_t)(S + s) * B + j];
  }
  float sigma2 = sigma2_of(t[j]);
  float evals = (den == 0.0f) ? 0.0f : (num / den);   // reference's den==0 guard
  out[j] = (evals - x[j]) / sigma2;
}

__global__ void zero_kernel(float* __restrict__ p, int n) {
  int i = blockIdx.x * blockDim.x + threadIdx.x;
  if (i < n) p[i] = 0.0f;
}

extern "C" void kernel_launch(void* const* d_in, const int* in_sizes, int n_in,
                              void* d_out, int out_size, void* d_ws, size_t ws_size,
                              hipStream_t stream) {
  const float* x  = (const float*)d_in[0];
  const float* t  = (const float*)d_in[1];
  const float* td = (const float*)d_in[2];
  float* out = (float*)d_out;
  float* ws  = (float*)d_ws;

  const int B = in_sizes[0];
  const int N = in_sizes[2];

  // Direct (no-atomic) path: S slices of CH=1024, partials in ws ([2][S][B]).
  int CH = MAXCH;
  int S  = (N + CH - 1) / CH;                       // 16 for N=16384
  size_t need = (size_t)2 * S * B * sizeof(float);

  if (ws_size >= need) {
    dim3 grid((B + BLK - 1) / BLK, S);              // (64, 16) = 1024 blocks
    gmm_partial<false><<<grid, BLK, 0, stream>>>(x, t, td, ws, N, B, CH);
    gmm_final<<<(B + BLK - 1) / BLK, BLK, 0, stream>>>(x, t, ws, out, B, S);
  } else {
    // Fallback: zero + atomic accumulate + final (3 dispatches)
    CH = 512;
    S  = (N + CH - 1) / CH;
    int nzero = 2 * B;
    zero_kernel<<<(nzero + 255) / 256, 256, 0, stream>>>(ws, nzero);
    dim3 grid((B + BLK - 1) / BLK, S);
    gmm_partial<true><<<grid, BLK, 0, stream>>>(x, t, td, ws, N, B, CH);
    gmm_final<<<(B + BLK - 1) / BLK, BLK, 0, stream>>>(x, t, ws, out, B, 1);
  }
}